// Round 1
// baseline (2803.199 us; speedup 1.0000x reference)
//
#include <hip/hip_runtime.h>
#include <hip/hip_bf16.h>
#include <math.h>

#define NPOS 16384   // B*H*W = 16*32*32
#define DD   512
#define GS   16      // scan prefetch depth

// ---------------- GEMM: C = A(MxK) @ B(KxN) + bias, epilogues ----------------
// epi 0: +bias   epi 1: +bias, sigmoid on cols >= sigcol   epi 2: +bias +res (residual)
#define BM 128
#define BN 128
#define BK 16

__global__ __launch_bounds__(256) void gemm_k(
    const float* __restrict__ A, const float* __restrict__ Bm,
    const float* __restrict__ bias, const float* res, float* C,
    int M, int N, int K, int epi, int sigcol)
{
  __shared__ float As[BK][BM+4];
  __shared__ float Bs[BK][BN+4];
  const int tid = threadIdx.x;
  const int bm = blockIdx.y * BM;
  const int bn = blockIdx.x * BN;
  const int tx = tid & 15;          // n dir
  const int ty = tid >> 4;          // m dir
  const int arow = tid >> 2;        // 0..63
  const int acol = (tid & 3) << 2;  // 0,4,8,12
  const int brow = tid >> 5;        // 0..7
  const int bcol = (tid & 31) << 2; // 0..124

  float acc[8][8];
  #pragma unroll
  for (int i = 0; i < 8; ++i)
    #pragma unroll
    for (int j = 0; j < 8; ++j) acc[i][j] = 0.f;

  for (int k0 = 0; k0 < K; k0 += BK) {
    #pragma unroll
    for (int h2 = 0; h2 < 2; ++h2) {
      int r = arow + h2 * 64;
      float4 a4 = *(const float4*)(A + (size_t)(bm + r) * K + (k0 + acol));
      As[acol+0][r] = a4.x; As[acol+1][r] = a4.y;
      As[acol+2][r] = a4.z; As[acol+3][r] = a4.w;
    }
    #pragma unroll
    for (int h2 = 0; h2 < 2; ++h2) {
      int r = brow + h2 * 8;
      *(float4*)(&Bs[r][bcol]) = *(const float4*)(Bm + (size_t)(k0 + r) * N + (bn + bcol));
    }
    __syncthreads();
    #pragma unroll
    for (int kk = 0; kk < BK; ++kk) {
      float4 a0 = *(const float4*)(&As[kk][ty*8]);
      float4 a1 = *(const float4*)(&As[kk][ty*8+4]);
      float4 b0 = *(const float4*)(&Bs[kk][tx*8]);
      float4 b1 = *(const float4*)(&Bs[kk][tx*8+4]);
      float af[8] = {a0.x,a0.y,a0.z,a0.w,a1.x,a1.y,a1.z,a1.w};
      float bf[8] = {b0.x,b0.y,b0.z,b0.w,b1.x,b1.y,b1.z,b1.w};
      #pragma unroll
      for (int i = 0; i < 8; ++i)
        #pragma unroll
        for (int j = 0; j < 8; ++j) acc[i][j] = fmaf(af[i], bf[j], acc[i][j]);
    }
    __syncthreads();
  }

  const bool dosig = (epi == 1) && (bn >= sigcol);  // bn multiple of 128, sigcol=512 -> uniform per block
  #pragma unroll
  for (int i = 0; i < 8; ++i) {
    size_t m = (size_t)(bm + ty*8 + i);
    float* crow = C + m * (size_t)N + bn + tx*8;
    const float* rrow = (epi == 2) ? (res + m * (size_t)N + bn + tx*8) : nullptr;
    #pragma unroll
    for (int jj = 0; jj < 2; ++jj) {
      float v[4];
      #pragma unroll
      for (int c = 0; c < 4; ++c) {
        int n = tx*8 + jj*4 + c;
        v[c] = acc[i][jj*4+c] + bias[bn + n];
        if (dosig) v[c] = 1.f / (1.f + expf(-v[c]));
      }
      if (epi == 2) {
        float4 rv = *(const float4*)(rrow + jj*4);
        v[0] += rv.x; v[1] += rv.y; v[2] += rv.z; v[3] += rv.w;
      }
      float4 o = {v[0], v[1], v[2], v[3]};
      *(float4*)(crow + jj*4) = o;
    }
  }
}

// ---------------- LayerNorm over D=512, one wave per position ----------------
__global__ __launch_bounds__(256) void ln_k(const float* __restrict__ x, const float* __restrict__ w,
                                            const float* __restrict__ bv, float* __restrict__ out)
{
  int gw = (blockIdx.x * 256 + threadIdx.x) >> 6;   // position
  int lane = threadIdx.x & 63;
  const float* xp = x + ((size_t)gw << 9) + lane * 8;
  float4 u0 = *(const float4*)xp;
  float4 u1 = *(const float4*)(xp + 4);
  float v[8] = {u0.x,u0.y,u0.z,u0.w,u1.x,u1.y,u1.z,u1.w};
  float s = 0.f;
  #pragma unroll
  for (int j = 0; j < 8; ++j) s += v[j];
  #pragma unroll
  for (int off = 32; off; off >>= 1) s += __shfl_xor(s, off, 64);
  float mu = s * (1.f/512.f);
  float q = 0.f;
  #pragma unroll
  for (int j = 0; j < 8; ++j) { float d = v[j] - mu; q += d*d; }
  #pragma unroll
  for (int off = 32; off; off >>= 1) q += __shfl_xor(q, off, 64);
  float rstd = rsqrtf(q * (1.f/512.f) + 1e-5f);
  int dch = lane * 8;
  float4 w0 = *(const float4*)(w + dch),  w1 = *(const float4*)(w + dch + 4);
  float4 b0 = *(const float4*)(bv + dch), b1 = *(const float4*)(bv + dch + 4);
  float wv[8] = {w0.x,w0.y,w0.z,w0.w,w1.x,w1.y,w1.z,w1.w};
  float bb[8] = {b0.x,b0.y,b0.z,b0.w,b1.x,b1.y,b1.z,b1.w};
  float o[8];
  #pragma unroll
  for (int j = 0; j < 8; ++j) o[j] = (v[j] - mu) * rstd * wv[j] + bb[j];
  float* op = out + ((size_t)gw << 9) + dch;
  float4 o0 = {o[0],o[1],o[2],o[3]}, o1 = {o[4],o[5],o[6],o[7]};
  *(float4*)op = o0;
  *(float4*)(op + 4) = o1;
}

// ---------------- depthwise 3x3 conv + bias + SiLU; x_in read from xg cols 0..511 ----------------
__global__ __launch_bounds__(256) void conv_k(const float* __restrict__ xg, const float* __restrict__ cw,
                                              const float* __restrict__ cb, float* __restrict__ u)
{
  int id = blockIdx.x * 256 + threadIdx.x;   // 0 .. NPOS*128
  int dq = id & 127;
  int pos = id >> 7;
  int ww = pos & 31, hh = (pos >> 5) & 31, b = pos >> 10;
  int d = dq << 2;
  float4 acc = *(const float4*)(cb + d);
  #pragma unroll
  for (int kh = 0; kh < 3; ++kh) {
    int yy = hh + kh - 1;
    if (yy < 0 || yy > 31) continue;
    #pragma unroll
    for (int kw = 0; kw < 3; ++kw) {
      int xx = ww + kw - 1;
      if (xx < 0 || xx > 31) continue;
      float4 xv = *(const float4*)(xg + ((size_t)((b << 10) + (yy << 5) + xx) << 10) + d);
      float4 wv = *(const float4*)(cw + (size_t)((kh*3 + kw) << 9) + d);
      acc.x = fmaf(xv.x, wv.x, acc.x);
      acc.y = fmaf(xv.y, wv.y, acc.y);
      acc.z = fmaf(xv.z, wv.z, acc.z);
      acc.w = fmaf(xv.w, wv.w, acc.w);
    }
  }
  acc.x = acc.x / (1.f + expf(-acc.x));
  acc.y = acc.y / (1.f + expf(-acc.y));
  acc.z = acc.z / (1.f + expf(-acc.z));
  acc.w = acc.w / (1.f + expf(-acc.w));
  *(float4*)(u + ((size_t)pos << 9) + d) = acc;
}

// ---------------- SSM scan: replicates reference clamped-a_pow cumsum exactly ----------------
// grid (8 chan-groups, 2 orientations, 16 batch), block 64. fwd stores 0.25*c*s; bwd adds.
__global__ __launch_bounds__(64) void scan_k(const float* __restrict__ u, const float* __restrict__ alog,
    const float* __restrict__ bvec, const float* __restrict__ cvec,
    float* rowp, float* colp)
{
  const int lane = threadIdx.x;
  const int cg = blockIdx.x;
  const int orient = blockIdx.y;
  const int b = blockIdx.z;
  const int d = (cg << 6) + lane;
  float a = 1.f / (1.f + expf(-alog[d]));
  a = fminf(fmaxf(a, 1e-4f), 1.f - 1e-4f);
  const float lna = logf(a);
  const float bb = bvec[d];
  const float sc = 0.25f * cvec[d];
  const float* ub = u + ((size_t)b << 19) + d;
  float* ob; int os;
  if (orient == 0) { ob = rowp + ((size_t)b << 19) + d; os = 512; }
  else             { ob = colp + ((size_t)b << 20) + d; os = 1024; }

  // forward
  {
    float cur[GS], nxt[GS];
    #pragma unroll
    for (int j = 0; j < GS; ++j) {
      int t = j; int p = orient ? (((t & 31) << 5) | (t >> 5)) : t;
      cur[j] = ub[(size_t)p << 9];
    }
    float r = 0.f;
    for (int g = 0; g < 1024 / GS; ++g) {
      int gn = g + 1;
      if (gn < 1024 / GS) {
        #pragma unroll
        for (int j = 0; j < GS; ++j) {
          int t = gn * GS + j; int p = orient ? (((t & 31) << 5) | (t >> 5)) : t;
          nxt[j] = ub[(size_t)p << 9];
        }
      }
      #pragma unroll
      for (int j = 0; j < GS; ++j) {
        int t = g * GS + j;
        float ap = fmaxf(expf((float)t * lna), 1e-20f);
        r += cur[j] * bb / ap;
        float s = r * ap;
        int p = orient ? (((t & 31) << 5) | (t >> 5)) : t;
        ob[(size_t)p * os] = sc * s;
      }
      #pragma unroll
      for (int j = 0; j < GS; ++j) cur[j] = nxt[j];
    }
  }
  // backward (scan reversed sequence; a_pow indexed by position in reversed seq)
  {
    float cur[GS], nxt[GS], po[GS], pn[GS];
    #pragma unroll
    for (int j = 0; j < GS; ++j) {
      int t = 1023 - j; int p = orient ? (((t & 31) << 5) | (t >> 5)) : t;
      cur[j] = ub[(size_t)p << 9];
      po[j]  = ob[(size_t)p * os];
    }
    float r = 0.f;
    for (int g = 0; g < 1024 / GS; ++g) {
      int gn = g + 1;
      if (gn < 1024 / GS) {
        #pragma unroll
        for (int j = 0; j < GS; ++j) {
          int jj = gn * GS + j; int t = 1023 - jj;
          int p = orient ? (((t & 31) << 5) | (t >> 5)) : t;
          nxt[j] = ub[(size_t)p << 9];
          pn[j]  = ob[(size_t)p * os];
        }
      }
      #pragma unroll
      for (int j = 0; j < GS; ++j) {
        int jj = g * GS + j;
        int t = 1023 - jj;
        float ap = fmaxf(expf((float)jj * lna), 1e-20f);
        r += cur[j] * bb / ap;
        float s = r * ap;
        int p = orient ? (((t & 31) << 5) | (t >> 5)) : t;
        ob[(size_t)p * os] = po[j] + sc * s;
      }
      #pragma unroll
      for (int j = 0; j < GS; ++j) { cur[j] = nxt[j]; po[j] = pn[j]; }
    }
  }
}

// ---------------- combine partials + d*u, multiply by gate -> yg (in place over rowp) ----------------
__global__ __launch_bounds__(256) void combine_k(const float* rowp, const float* __restrict__ xg,
    const float* __restrict__ u, const float* __restrict__ dvec, float* yg)
{
  int id = blockIdx.x * 256 + threadIdx.x;
  int dq = id & 127; int pos = id >> 7;
  int d = dq << 2;
  float4 rv = *(const float4*)(rowp + ((size_t)pos << 9) + d);
  float4 cv = *(const float4*)(xg + ((size_t)pos << 10) + d);          // col partial (reused x_in slot)
  float4 uv = *(const float4*)(u + ((size_t)pos << 9) + d);
  float4 dd = *(const float4*)(dvec + d);
  float4 gv = *(const float4*)(xg + ((size_t)pos << 10) + 512 + d);    // gate (already sigmoided)
  float4 o;
  o.x = (rv.x + cv.x + dd.x * uv.x) * gv.x;
  o.y = (rv.y + cv.y + dd.y * uv.y) * gv.y;
  o.z = (rv.z + cv.z + dd.z * uv.z) * gv.z;
  o.w = (rv.w + cv.w + dd.w * uv.w) * gv.w;
  *(float4*)(yg + ((size_t)pos << 9) + d) = o;
}

// ---------------- mean over 1024 positions -> (16, 512) ----------------
__global__ __launch_bounds__(64) void reduce_k(const float* __restrict__ hn, float* __restrict__ out)
{
  int d = blockIdx.y * 64 + threadIdx.x;
  int b = blockIdx.x;
  const float* p = hn + ((size_t)b << 19) + d;
  float s0 = 0.f, s1 = 0.f, s2 = 0.f, s3 = 0.f;
  for (int t = 0; t < 1024; t += 4) {
    s0 += p[(size_t)(t+0) << 9];
    s1 += p[(size_t)(t+1) << 9];
    s2 += p[(size_t)(t+2) << 9];
    s3 += p[(size_t)(t+3) << 9];
  }
  out[b * 512 + d] = (s0 + s1 + s2 + s3) * (1.f / 1024.f);
}

extern "C" void kernel_launch(void* const* d_in, const int* in_sizes, int n_in,
                              void* d_out, int out_size, void* d_ws, size_t ws_size,
                              hipStream_t stream)
{
  const float* tokens = (const float*)d_in[0];
  const float* in_w   = (const float*)d_in[1];
  const float* in_b   = (const float*)d_in[2];
  const float* nw     = (const float*)d_in[3];
  const float* nb     = (const float*)d_in[4];
  const float* iw     = (const float*)d_in[5];
  const float* ib     = (const float*)d_in[6];
  const float* cw     = (const float*)d_in[7];
  const float* cb     = (const float*)d_in[8];
  const float* al     = (const float*)d_in[9];
  const float* bbv    = (const float*)d_in[10];
  const float* ccv    = (const float*)d_in[11];
  const float* ddv    = (const float*)d_in[12];
  const float* ow     = (const float*)d_in[13];
  const float* obv    = (const float*)d_in[14];
  const float* onw    = (const float*)d_in[15];
  const float* onb    = (const float*)d_in[16];

  float* x  = (float*)d_ws;                    // (16384, 512) residual stream
  float* h  = x  + (size_t)NPOS * DD;          // (16384, 512) h / u / final normed
  float* xg = h  + (size_t)NPOS * DD;          // (16384, 1024) x_in+gate; x_in half reused as col partial
  float* y  = xg + (size_t)NPOS * 2 * DD;      // (16384, 512) row partial / yg

  // x = tokens @ in_proj_w + b
  gemm_k<<<dim3(4, 128), 256, 0, stream>>>(tokens, in_w, in_b, nullptr, x, NPOS, 512, 768, 0, 0);

  for (int i = 0; i < 4; ++i) {
    ln_k<<<4096, 256, 0, stream>>>(x, nw + i*512, nb + i*512, h);
    gemm_k<<<dim3(8, 128), 256, 0, stream>>>(h, iw + (size_t)i*512*1024, ib + i*1024, nullptr,
                                             xg, NPOS, 1024, 512, 1, 512);
    conv_k<<<8192, 256, 0, stream>>>(xg, cw + i*9*512, cb + i*512, h);          // u -> h
    scan_k<<<dim3(8, 2, 16), 64, 0, stream>>>(h, al + i*512, bbv + i*512, ccv + i*512, y, xg);
    combine_k<<<8192, 256, 0, stream>>>(y, xg, h, ddv + i*512, y);              // yg -> y
    gemm_k<<<dim3(4, 128), 256, 0, stream>>>(y, ow + (size_t)i*512*512, obv + i*512, x,
                                             x, NPOS, 512, 512, 2, 0);          // x += yg@W + b
  }

  ln_k<<<4096, 256, 0, stream>>>(x, onw, onb, h);
  reduce_k<<<dim3(16, 8), 64, 0, stream>>>(h, (float*)d_out);
}

// Round 2
// 1996.765 us; speedup vs baseline: 1.4039x; 1.4039x over previous
//
#include <hip/hip_runtime.h>
#include <hip/hip_bf16.h>
#include <math.h>

#define NPOS 16384   // B*H*W = 16*32*32
#define DD   512

// ---------------- GEMM: C = A(MxK) @ B(KxN) + bias, epilogues ----------------
// epi 0: +bias
// epi 1: +bias; cols < sigcol -> plane C (ld 512); cols >= sigcol -> sigmoid -> plane C2 (ld 512)
// epi 2: +bias +res (residual add), ld = N
#define BM 128
#define BN 128
#define BK 16

__global__ __launch_bounds__(256) void gemm_k(
    const float* __restrict__ A, const float* __restrict__ Bm,
    const float* __restrict__ bias, const float* res, float* C, float* C2,
    int M, int N, int K, int epi, int sigcol)
{
  __shared__ float As[BK][BM+4];
  __shared__ float Bs[BK][BN+4];
  const int tid = threadIdx.x;
  const int bm = blockIdx.y * BM;
  const int bn = blockIdx.x * BN;
  const int tx = tid & 15;          // n dir
  const int ty = tid >> 4;          // m dir
  const int arow = tid >> 2;        // 0..63
  const int acol = (tid & 3) << 2;  // 0,4,8,12
  const int brow = tid >> 5;        // 0..7
  const int bcol = (tid & 31) << 2; // 0..124

  float acc[8][8];
  #pragma unroll
  for (int i = 0; i < 8; ++i)
    #pragma unroll
    for (int j = 0; j < 8; ++j) acc[i][j] = 0.f;

  for (int k0 = 0; k0 < K; k0 += BK) {
    #pragma unroll
    for (int h2 = 0; h2 < 2; ++h2) {
      int r = arow + h2 * 64;
      float4 a4 = *(const float4*)(A + (size_t)(bm + r) * K + (k0 + acol));
      As[acol+0][r] = a4.x; As[acol+1][r] = a4.y;
      As[acol+2][r] = a4.z; As[acol+3][r] = a4.w;
    }
    #pragma unroll
    for (int h2 = 0; h2 < 2; ++h2) {
      int r = brow + h2 * 8;
      *(float4*)(&Bs[r][bcol]) = *(const float4*)(Bm + (size_t)(k0 + r) * N + (bn + bcol));
    }
    __syncthreads();
    #pragma unroll
    for (int kk = 0; kk < BK; ++kk) {
      float4 a0 = *(const float4*)(&As[kk][ty*8]);
      float4 a1 = *(const float4*)(&As[kk][ty*8+4]);
      float4 b0 = *(const float4*)(&Bs[kk][tx*8]);
      float4 b1 = *(const float4*)(&Bs[kk][tx*8+4]);
      float af[8] = {a0.x,a0.y,a0.z,a0.w,a1.x,a1.y,a1.z,a1.w};
      float bf[8] = {b0.x,b0.y,b0.z,b0.w,b1.x,b1.y,b1.z,b1.w};
      #pragma unroll
      for (int i = 0; i < 8; ++i)
        #pragma unroll
        for (int j = 0; j < 8; ++j) acc[i][j] = fmaf(af[i], bf[j], acc[i][j]);
    }
    __syncthreads();
  }

  const bool dosig = (epi == 1) && (bn >= sigcol);  // uniform per block (bn mult of 128)
  float* Co; int ldo; int nbase;
  if (epi == 1) { ldo = 512; if (bn >= sigcol) { Co = C2; nbase = bn - sigcol; } else { Co = C; nbase = bn; } }
  else          { Co = C; ldo = N; nbase = bn; }

  #pragma unroll
  for (int i = 0; i < 8; ++i) {
    size_t m = (size_t)(bm + ty*8 + i);
    float* crow = Co + m * (size_t)ldo + nbase + tx*8;
    const float* rrow = (epi == 2) ? (res + m * (size_t)N + bn + tx*8) : nullptr;
    #pragma unroll
    for (int jj = 0; jj < 2; ++jj) {
      float v[4];
      #pragma unroll
      for (int c = 0; c < 4; ++c) {
        int n = tx*8 + jj*4 + c;
        v[c] = acc[i][jj*4+c] + bias[bn + n];
        if (dosig) v[c] = 1.f / (1.f + expf(-v[c]));
      }
      if (epi == 2) {
        float4 rv = *(const float4*)(rrow + jj*4);
        v[0] += rv.x; v[1] += rv.y; v[2] += rv.z; v[3] += rv.w;
      }
      float4 o = {v[0], v[1], v[2], v[3]};
      *(float4*)(crow + jj*4) = o;
    }
  }
}

// ---------------- LayerNorm over D=512, one wave per position ----------------
__global__ __launch_bounds__(256) void ln_k(const float* __restrict__ x, const float* __restrict__ w,
                                            const float* __restrict__ bv, float* __restrict__ out)
{
  int gw = (blockIdx.x * 256 + threadIdx.x) >> 6;   // position
  int lane = threadIdx.x & 63;
  const float* xp = x + ((size_t)gw << 9) + lane * 8;
  float4 u0 = *(const float4*)xp;
  float4 u1 = *(const float4*)(xp + 4);
  float v[8] = {u0.x,u0.y,u0.z,u0.w,u1.x,u1.y,u1.z,u1.w};
  float s = 0.f;
  #pragma unroll
  for (int j = 0; j < 8; ++j) s += v[j];
  #pragma unroll
  for (int off = 32; off; off >>= 1) s += __shfl_xor(s, off, 64);
  float mu = s * (1.f/512.f);
  float q = 0.f;
  #pragma unroll
  for (int j = 0; j < 8; ++j) { float d = v[j] - mu; q += d*d; }
  #pragma unroll
  for (int off = 32; off; off >>= 1) q += __shfl_xor(q, off, 64);
  float rstd = rsqrtf(q * (1.f/512.f) + 1e-5f);
  int dch = lane * 8;
  float4 w0 = *(const float4*)(w + dch),  w1 = *(const float4*)(w + dch + 4);
  float4 b0 = *(const float4*)(bv + dch), b1 = *(const float4*)(bv + dch + 4);
  float wv[8] = {w0.x,w0.y,w0.z,w0.w,w1.x,w1.y,w1.z,w1.w};
  float bb[8] = {b0.x,b0.y,b0.z,b0.w,b1.x,b1.y,b1.z,b1.w};
  float o[8];
  #pragma unroll
  for (int j = 0; j < 8; ++j) o[j] = (v[j] - mu) * rstd * wv[j] + bb[j];
  float* op = out + ((size_t)gw << 9) + dch;
  float4 o0 = {o[0],o[1],o[2],o[3]}, o1 = {o[4],o[5],o[6],o[7]};
  *(float4*)op = o0;
  *(float4*)(op + 4) = o1;
}

// ---------------- depthwise 3x3 conv + bias + SiLU; x_in plane (ld 512) -> u ----------------
__global__ __launch_bounds__(256) void conv_k(const float* __restrict__ xin, const float* __restrict__ cw,
                                              const float* __restrict__ cb, float* __restrict__ u)
{
  int id = blockIdx.x * 256 + threadIdx.x;   // 0 .. NPOS*128
  int dq = id & 127;
  int pos = id >> 7;
  int ww = pos & 31, hh = (pos >> 5) & 31, b = pos >> 10;
  int d = dq << 2;
  float4 acc = *(const float4*)(cb + d);
  #pragma unroll
  for (int kh = 0; kh < 3; ++kh) {
    int yy = hh + kh - 1;
    if (yy < 0 || yy > 31) continue;
    #pragma unroll
    for (int kw = 0; kw < 3; ++kw) {
      int xx = ww + kw - 1;
      if (xx < 0 || xx > 31) continue;
      float4 xv = *(const float4*)(xin + ((size_t)((b << 10) + (yy << 5) + xx) << 9) + d);
      float4 wv = *(const float4*)(cw + (size_t)((kh*3 + kw) << 9) + d);
      acc.x = fmaf(xv.x, wv.x, acc.x);
      acc.y = fmaf(xv.y, wv.y, acc.y);
      acc.z = fmaf(xv.z, wv.z, acc.z);
      acc.w = fmaf(xv.w, wv.w, acc.w);
    }
  }
  acc.x = acc.x / (1.f + expf(-acc.x));
  acc.y = acc.y / (1.f + expf(-acc.y));
  acc.z = acc.z / (1.f + expf(-acc.z));
  acc.w = acc.w / (1.f + expf(-acc.w));
  *(float4*)(u + ((size_t)pos << 9) + d) = acc;
}

// ================= Parallel clamped-cumsum scan =================
// Semantics per channel d: a=clip(sigmoid(alog),1e-4,1-1e-4); ap_t=max(exp(t*ln a),1e-20)
// fwd: r_t = sum_{k<=t} u_k*b/ap_k; s_t = r_t*ap_t
// bwd: same on reversed sequence (ap indexed by reversed position)
// out_t = 0.25*c*(s_fwd_t + s_bwd_t) per orientation; orientations summed; + d*u; * gate.
// Time split into 32 chunks of 32. A: chunk sums. B: exclusive prefix/suffix. C: scan w/ carry.

__device__ __forceinline__ float sig_a(float al) {
  float a = 1.f / (1.f + expf(-al));
  return fminf(fmaxf(a, 1e-4f), 1.f - 1e-4f);
}

// grid (8 cg, 32 chunk, 32 = b*2+orient), block 64
__global__ __launch_bounds__(64) void scanA_k(const float* __restrict__ u, const float* __restrict__ alog,
    const float* __restrict__ bvec, float* __restrict__ carF, float* __restrict__ carB)
{
  const int lane = threadIdx.x;
  const int cg = blockIdx.x, c = blockIdx.y;
  const int b = blockIdx.z >> 1, orient = blockIdx.z & 1;
  const int d = (cg << 6) + lane;
  const float a = sig_a(alog[d]);
  const float lna = logf(a);
  const float bb = bvec[d];
  const float* ub = u + ((size_t)b << 19) + d;

  float uv[32];
  #pragma unroll
  for (int j = 0; j < 32; ++j) {
    int p = orient ? ((j << 5) | c) : ((c << 5) + j);
    uv[j] = ub[(size_t)p << 9];
  }
  // fwd chunk sum: t = 32c + j, ap = max(a^t, 1e-20), multiplicative
  float apr = expf((float)(c << 5) * lna);
  float sF = 0.f;
  #pragma unroll
  for (int j = 0; j < 32; ++j) {
    float ap = fmaxf(apr, 1e-20f);
    sF += uv[j] * bb / ap;
    apr *= a;
  }
  // bwd chunk sum: jj = 1023 - t; j desc -> jj asc from 32*(31-c)
  float aprB = expf((float)((31 - c) << 5) * lna);
  float sB = 0.f;
  #pragma unroll
  for (int j = 31; j >= 0; --j) {
    float ap = fmaxf(aprB, 1e-20f);
    sB += uv[j] * bb / ap;
    aprB *= a;
  }
  size_t idx = ((size_t)blockIdx.z * 32 + c) * 512 + d;
  carF[idx] = sF;
  carB[idx] = sB;
}

// exclusive prefix (fwd) / exclusive suffix (bwd) over 32 chunks; 16384 lanes
__global__ __launch_bounds__(256) void scanB_k(float* __restrict__ carF, float* __restrict__ carB)
{
  int id = blockIdx.x * 256 + threadIdx.x;   // 0..16383
  int d = id & 511; int q = id >> 9;         // q = b*2+orient
  float* pF = carF + (size_t)q * 32 * 512 + d;
  float run = 0.f;
  #pragma unroll
  for (int c = 0; c < 32; ++c) { float v = pF[c * 512]; pF[c * 512] = run; run += v; }
  float* pB = carB + (size_t)q * 32 * 512 + d;
  run = 0.f;
  #pragma unroll
  for (int c = 31; c >= 0; --c) { float v = pB[c * 512]; pB[c * 512] = run; run += v; }
}

// row orientation: writes y = 0.25*c*(s_fwd + s_bwd). grid (8 cg, 32 chunk, 16 b), block 64
__global__ __launch_bounds__(64) void scanC_row_k(const float* __restrict__ u, const float* __restrict__ alog,
    const float* __restrict__ bvec, const float* __restrict__ cvec,
    const float* __restrict__ carF, const float* __restrict__ carB, float* __restrict__ y)
{
  const int lane = threadIdx.x;
  const int cg = blockIdx.x, c = blockIdx.y, b = blockIdx.z;
  const int d = (cg << 6) + lane;
  const float a = sig_a(alog[d]);
  const float lna = logf(a);
  const float bb = bvec[d];
  const float sc = 0.25f * cvec[d];
  const float* ub = u + ((size_t)b << 19) + d;
  size_t cidx = ((size_t)(b * 2 + 0) * 32 + c) * 512 + d;

  float uv[32], sf[32];
  #pragma unroll
  for (int j = 0; j < 32; ++j) uv[j] = ub[(size_t)((c << 5) + j) << 9];

  float r = carF[cidx];
  float apr = expf((float)(c << 5) * lna);
  #pragma unroll
  for (int j = 0; j < 32; ++j) {
    float ap = fmaxf(apr, 1e-20f);
    r += uv[j] * bb / ap;
    sf[j] = r * ap;
    apr *= a;
  }
  float r2 = carB[cidx];
  float aprB = expf((float)((31 - c) << 5) * lna);
  float* yb = y + ((size_t)b << 19) + d;
  #pragma unroll
  for (int j = 31; j >= 0; --j) {
    float ap = fmaxf(aprB, 1e-20f);
    r2 += uv[j] * bb / ap;
    yb[(size_t)((c << 5) + j) << 9] = sc * (sf[j] + r2 * ap);
    aprB *= a;
  }
}

// col orientation + combine: y = (y + 0.25*c*(sf+sb) + d*u) * gate. Runs after scanC_row_k.
__global__ __launch_bounds__(64) void scanC_col_k(const float* __restrict__ u, const float* __restrict__ alog,
    const float* __restrict__ bvec, const float* __restrict__ cvec, const float* __restrict__ dvec,
    const float* __restrict__ carF, const float* __restrict__ carB,
    const float* __restrict__ gate, float* __restrict__ y)
{
  const int lane = threadIdx.x;
  const int cg = blockIdx.x, c = blockIdx.y, b = blockIdx.z;
  const int d = (cg << 6) + lane;
  const float a = sig_a(alog[d]);
  const float lna = logf(a);
  const float bb = bvec[d];
  const float sc = 0.25f * cvec[d];
  const float dd = dvec[d];
  const float* ub = u + ((size_t)b << 19) + d;
  size_t cidx = ((size_t)(b * 2 + 1) * 32 + c) * 512 + d;

  float uv[32], sf[32];
  #pragma unroll
  for (int j = 0; j < 32; ++j) uv[j] = ub[(size_t)((j << 5) | c) << 9];

  float r = carF[cidx];
  float apr = expf((float)(c << 5) * lna);
  #pragma unroll
  for (int j = 0; j < 32; ++j) {
    float ap = fmaxf(apr, 1e-20f);
    r += uv[j] * bb / ap;
    sf[j] = r * ap;
    apr *= a;
  }
  float r2 = carB[cidx];
  float aprB = expf((float)((31 - c) << 5) * lna);
  float* yb = y + ((size_t)b << 19) + d;
  const float* gb = gate + ((size_t)b << 19) + d;
  #pragma unroll
  for (int j = 31; j >= 0; --j) {
    float ap = fmaxf(aprB, 1e-20f);
    r2 += uv[j] * bb / ap;
    size_t off = (size_t)((j << 5) | c) << 9;
    float val = yb[off] + sc * (sf[j] + r2 * ap) + dd * uv[j];
    yb[off] = val * gb[off];
    aprB *= a;
  }
}

// ---------------- mean over 1024 positions -> (16, 512) ----------------
__global__ __launch_bounds__(64) void reduce_k(const float* __restrict__ hn, float* __restrict__ out)
{
  int d = blockIdx.y * 64 + threadIdx.x;
  int b = blockIdx.x;
  const float* p = hn + ((size_t)b << 19) + d;
  float s0 = 0.f, s1 = 0.f, s2 = 0.f, s3 = 0.f;
  for (int t = 0; t < 1024; t += 4) {
    s0 += p[(size_t)(t+0) << 9];
    s1 += p[(size_t)(t+1) << 9];
    s2 += p[(size_t)(t+2) << 9];
    s3 += p[(size_t)(t+3) << 9];
  }
  out[b * 512 + d] = (s0 + s1 + s2 + s3) * (1.f / 1024.f);
}

extern "C" void kernel_launch(void* const* d_in, const int* in_sizes, int n_in,
                              void* d_out, int out_size, void* d_ws, size_t ws_size,
                              hipStream_t stream)
{
  const float* tokens = (const float*)d_in[0];
  const float* in_w   = (const float*)d_in[1];
  const float* in_b   = (const float*)d_in[2];
  const float* nw     = (const float*)d_in[3];
  const float* nb     = (const float*)d_in[4];
  const float* iw     = (const float*)d_in[5];
  const float* ib     = (const float*)d_in[6];
  const float* cw     = (const float*)d_in[7];
  const float* cb     = (const float*)d_in[8];
  const float* al     = (const float*)d_in[9];
  const float* bbv    = (const float*)d_in[10];
  const float* ccv    = (const float*)d_in[11];
  const float* ddv    = (const float*)d_in[12];
  const float* ow     = (const float*)d_in[13];
  const float* obv    = (const float*)d_in[14];
  const float* onw    = (const float*)d_in[15];
  const float* onb    = (const float*)d_in[16];

  float* x    = (float*)d_ws;                  // (16384, 512) residual stream
  float* h    = x    + (size_t)NPOS * DD;      // (16384, 512) h / u / final normed
  float* xin  = h    + (size_t)NPOS * DD;      // (16384, 512) x_in plane; carries after conv
  float* gate = xin  + (size_t)NPOS * DD;      // (16384, 512) gate plane (sigmoided)
  float* y    = gate + (size_t)NPOS * DD;      // (16384, 512) scan output / yg
  float* carF = xin;                           // 16*2*32*512 floats = 2 MB (xin free post-conv)
  float* carB = xin + 16 * 2 * 32 * 512;

  // x = tokens @ in_proj_w + b
  gemm_k<<<dim3(4, 128), 256, 0, stream>>>(tokens, in_w, in_b, nullptr, x, nullptr,
                                           NPOS, 512, 768, 0, 0);

  for (int i = 0; i < 4; ++i) {
    ln_k<<<4096, 256, 0, stream>>>(x, nw + i*512, nb + i*512, h);
    gemm_k<<<dim3(8, 128), 256, 0, stream>>>(h, iw + (size_t)i*512*1024, ib + i*1024, nullptr,
                                             xin, gate, NPOS, 1024, 512, 1, 512);
    conv_k<<<8192, 256, 0, stream>>>(xin, cw + i*9*512, cb + i*512, h);          // u -> h
    scanA_k<<<dim3(8, 32, 32), 64, 0, stream>>>(h, al + i*512, bbv + i*512, carF, carB);
    scanB_k<<<64, 256, 0, stream>>>(carF, carB);
    scanC_row_k<<<dim3(8, 32, 16), 64, 0, stream>>>(h, al + i*512, bbv + i*512, ccv + i*512,
                                                    carF, carB, y);
    scanC_col_k<<<dim3(8, 32, 16), 64, 0, stream>>>(h, al + i*512, bbv + i*512, ccv + i*512,
                                                    ddv + i*512, carF, carB, gate, y);
    gemm_k<<<dim3(4, 128), 256, 0, stream>>>(y, ow + (size_t)i*512*512, obv + i*512, x,
                                             x, nullptr, NPOS, 512, 512, 2, 0);  // x += yg@W + b
  }

  ln_k<<<4096, 256, 0, stream>>>(x, onw, onb, h);
  reduce_k<<<dim3(16, 8), 64, 0, stream>>>(h, (float*)d_out);
}

// Round 3
// 990.212 us; speedup vs baseline: 2.8309x; 2.0165x over previous
//
#include <hip/hip_runtime.h>
#include <hip/hip_bf16.h>
#include <math.h>

#define NPOS 16384   // B*H*W = 16*32*32
#define DD   512
#define PP   ((size_t)NPOS * DD)   // 8388608 elements per plane

typedef __bf16 bf16x8 __attribute__((ext_vector_type(8)));
typedef float  f32x4  __attribute__((ext_vector_type(4)));

// async global->LDS, 16 B per lane; LDS dest = wave-uniform base + lane*16
__device__ __forceinline__ void g2lds16(const void* g, void* l) {
  __builtin_amdgcn_global_load_lds(
      (__attribute__((address_space(1))) void*)g,
      (__attribute__((address_space(3))) void*)l, 16, 0, 0);
}

// ================= bf16 MFMA GEMM (m97 structure) =================
// C = A(MxK) @ Bt^T + bias.  A: MxK bf16 (ld K). Bt: NxK bf16 (ld K).
// epi 0: C0 fp32 (ld N) = acc + bias
// epi 1: N=1024; cols<512 -> C0 (ld 512); cols>=512 -> sigmoid -> C1 (ld 512)
// epi 2: C0 fp32 (ld N) = acc + bias + res
// Tiles: 128x128, BK=32. 4 waves, each 64x64 (4x4 MFMA 16x16x32 tiles).
// LDS layout [row][k] 32 bf16/row with 16B-slot XOR swizzle: slot ^= (row>>1)&3
// (keeps staging contiguous for global_load_lds, makes frag ds_read_b128 2-way = free).
__global__ __launch_bounds__(256) void gemm_bf_k(
    const __bf16* __restrict__ A, const __bf16* __restrict__ Bt,
    const float* __restrict__ bias, const float* __restrict__ res,
    float* __restrict__ C0, float* __restrict__ C1,
    int N, int K, int epi)
{
  __shared__ __bf16 Asm[128 * 32];
  __shared__ __bf16 Bsm[128 * 32];
  const int tid  = threadIdx.x;
  const int wave = tid >> 6;
  const int lane = tid & 63;
  const int quad = lane >> 4;
  const int l16  = lane & 15;
  const int bm = blockIdx.y * 128;
  const int bn = blockIdx.x * 128;
  const int wm = (wave >> 1) << 6;
  const int wn = (wave & 1) << 6;

  const int srow   = lane >> 2;                                  // row within 16-row stage
  const int schunk = (((lane & 3) ^ ((lane >> 3) & 3)) << 3);    // swizzled k-chunk (elements)

  f32x4 acc[4][4];
  const f32x4 z4 = {0.f, 0.f, 0.f, 0.f};
  #pragma unroll
  for (int i = 0; i < 4; ++i)
    #pragma unroll
    for (int j = 0; j < 4; ++j) acc[i][j] = z4;

  const __bf16* Ab = A  + (size_t)bm * K;
  const __bf16* Bb = Bt + (size_t)bn * K;

  for (int k0 = 0; k0 < K; k0 += 32) {
    #pragma unroll
    for (int c = 0; c < 2; ++c) {
      const int cc = wave * 2 + c;                 // stage-call id, wave-uniform
      g2lds16(Ab + (size_t)(cc * 16 + srow) * K + k0 + schunk, Asm + cc * 512);
      g2lds16(Bb + (size_t)(cc * 16 + srow) * K + k0 + schunk, Bsm + cc * 512);
    }
    __syncthreads();
    bf16x8 af[4], bg[4];
    #pragma unroll
    for (int i = 0; i < 4; ++i) {
      int m = wm + i * 16 + l16;
      af[i] = *(const bf16x8*)(Asm + m * 32 + ((quad ^ ((m >> 1) & 3)) << 3));
    }
    #pragma unroll
    for (int j = 0; j < 4; ++j) {
      int n = wn + j * 16 + l16;
      bg[j] = *(const bf16x8*)(Bsm + n * 32 + ((quad ^ ((n >> 1) & 3)) << 3));
    }
    #pragma unroll
    for (int i = 0; i < 4; ++i)
      #pragma unroll
      for (int j = 0; j < 4; ++j)
        acc[i][j] = __builtin_amdgcn_mfma_f32_16x16x32_bf16(af[i], bg[j], acc[i][j], 0, 0, 0);
    __syncthreads();
  }

  // epilogue. C/D layout: col = lane&15, row = quad*4 + reg  [m89-verified]
  float* Co; int ldo, nb; bool dosig = false;
  if (epi == 1) {
    ldo = 512;
    if (bn >= 512) { Co = C1; nb = bn - 512; dosig = true; }
    else           { Co = C0; nb = bn; }
  } else { Co = C0; ldo = N; nb = bn; }

  #pragma unroll
  for (int j = 0; j < 4; ++j) {
    const int col = wn + j * 16 + l16;
    const float bv = bias[bn + col];
    #pragma unroll
    for (int i = 0; i < 4; ++i) {
      const int row0 = bm + wm + i * 16 + quad * 4;
      #pragma unroll
      for (int r = 0; r < 4; ++r) {
        float v = acc[i][j][r] + bv;
        if (dosig) v = 1.f / (1.f + expf(-v));
        size_t off = (size_t)(row0 + r) * ldo + nb + col;
        if (epi == 2) v += res[off];
        Co[off] = v;
      }
    }
  }
}

// ---------------- fp32 -> bf16 elementwise (tokens) ----------------
__global__ __launch_bounds__(256) void cvt_k(const float* __restrict__ s, __bf16* __restrict__ d)
{
  size_t i = ((size_t)blockIdx.x * 256 + threadIdx.x) * 8;
  float4 a = *(const float4*)(s + i);
  float4 b = *(const float4*)(s + i + 4);
  bf16x8 v;
  v[0] = (__bf16)a.x; v[1] = (__bf16)a.y; v[2] = (__bf16)a.z; v[3] = (__bf16)a.w;
  v[4] = (__bf16)b.x; v[5] = (__bf16)b.y; v[6] = (__bf16)b.z; v[7] = (__bf16)b.w;
  *(bf16x8*)(d + i) = v;
}

// ---------------- transpose KxN fp32 -> NxK bf16 (weights) ----------------
__global__ __launch_bounds__(256) void tr_k(const float* __restrict__ src, __bf16* __restrict__ dst,
                                            int K, int N, size_t sstr, size_t dstr)
{
  __shared__ float t[32][33];
  const float* s = src + blockIdx.z * sstr;
  __bf16* d = dst + blockIdx.z * dstr;
  int n0 = blockIdx.x * 32, k0 = blockIdx.y * 32;
  int tx = threadIdx.x & 31, ty = threadIdx.x >> 5;   // 32x8
  #pragma unroll
  for (int i = 0; i < 4; ++i)
    t[ty + i * 8][tx] = s[(size_t)(k0 + ty + i * 8) * N + n0 + tx];
  __syncthreads();
  #pragma unroll
  for (int i = 0; i < 4; ++i)
    d[(size_t)(n0 + ty + i * 8) * K + k0 + tx] = (__bf16)t[tx][ty + i * 8];
}

// ---------------- LayerNorm over D=512, one wave per position, bf16 out ----------------
__global__ __launch_bounds__(256) void ln_k(const float* __restrict__ x, const float* __restrict__ w,
                                            const float* __restrict__ bv, __bf16* __restrict__ out)
{
  int gw = (blockIdx.x * 256 + threadIdx.x) >> 6;   // position
  int lane = threadIdx.x & 63;
  const float* xp = x + ((size_t)gw << 9) + lane * 8;
  float4 u0 = *(const float4*)xp;
  float4 u1 = *(const float4*)(xp + 4);
  float v[8] = {u0.x,u0.y,u0.z,u0.w,u1.x,u1.y,u1.z,u1.w};
  float s = 0.f;
  #pragma unroll
  for (int j = 0; j < 8; ++j) s += v[j];
  #pragma unroll
  for (int off = 32; off; off >>= 1) s += __shfl_xor(s, off, 64);
  float mu = s * (1.f/512.f);
  float q = 0.f;
  #pragma unroll
  for (int j = 0; j < 8; ++j) { float d = v[j] - mu; q += d*d; }
  #pragma unroll
  for (int off = 32; off; off >>= 1) q += __shfl_xor(q, off, 64);
  float rstd = rsqrtf(q * (1.f/512.f) + 1e-5f);
  int dch = lane * 8;
  float4 w0 = *(const float4*)(w + dch),  w1 = *(const float4*)(w + dch + 4);
  float4 b0 = *(const float4*)(bv + dch), b1 = *(const float4*)(bv + dch + 4);
  float wv[8] = {w0.x,w0.y,w0.z,w0.w,w1.x,w1.y,w1.z,w1.w};
  float bb[8] = {b0.x,b0.y,b0.z,b0.w,b1.x,b1.y,b1.z,b1.w};
  bf16x8 ov;
  #pragma unroll
  for (int j = 0; j < 8; ++j) ov[j] = (__bf16)((v[j] - mu) * rstd * wv[j] + bb[j]);
  *(bf16x8*)(out + ((size_t)gw << 9) + dch) = ov;
}

// ---------------- depthwise 3x3 conv + bias + SiLU; xin plane (ld 512) -> u ----------------
__global__ __launch_bounds__(256) void conv_k(const float* __restrict__ xin, const float* __restrict__ cw,
                                              const float* __restrict__ cb, float* __restrict__ u)
{
  int id = blockIdx.x * 256 + threadIdx.x;
  int dq = id & 127;
  int pos = id >> 7;
  int ww = pos & 31, hh = (pos >> 5) & 31, b = pos >> 10;
  int d = dq << 2;
  float4 acc = *(const float4*)(cb + d);
  #pragma unroll
  for (int kh = 0; kh < 3; ++kh) {
    int yy = hh + kh - 1;
    if (yy < 0 || yy > 31) continue;
    #pragma unroll
    for (int kw = 0; kw < 3; ++kw) {
      int xx = ww + kw - 1;
      if (xx < 0 || xx > 31) continue;
      float4 xv = *(const float4*)(xin + ((size_t)((b << 10) + (yy << 5) + xx) << 9) + d);
      float4 wv = *(const float4*)(cw + (size_t)((kh*3 + kw) << 9) + d);
      acc.x = fmaf(xv.x, wv.x, acc.x);
      acc.y = fmaf(xv.y, wv.y, acc.y);
      acc.z = fmaf(xv.z, wv.z, acc.z);
      acc.w = fmaf(xv.w, wv.w, acc.w);
    }
  }
  acc.x = acc.x / (1.f + expf(-acc.x));
  acc.y = acc.y / (1.f + expf(-acc.y));
  acc.z = acc.z / (1.f + expf(-acc.z));
  acc.w = acc.w / (1.f + expf(-acc.w));
  *(float4*)(u + ((size_t)pos << 9) + d) = acc;
}

// ================= Parallel clamped-cumsum scan (exact reference semantics) =================
__device__ __forceinline__ float sig_a(float al) {
  float a = 1.f / (1.f + expf(-al));
  return fminf(fmaxf(a, 1e-4f), 1.f - 1e-4f);
}

// grid (8 cg, 32 chunk, 32 = b*2+orient), block 64
__global__ __launch_bounds__(64) void scanA_k(const float* __restrict__ u, const float* __restrict__ alog,
    const float* __restrict__ bvec, float* __restrict__ carF, float* __restrict__ carB)
{
  const int lane = threadIdx.x;
  const int cg = blockIdx.x, c = blockIdx.y;
  const int b = blockIdx.z >> 1, orient = blockIdx.z & 1;
  const int d = (cg << 6) + lane;
  const float a = sig_a(alog[d]);
  const float lna = logf(a);
  const float bb = bvec[d];
  const float* ub = u + ((size_t)b << 19) + d;

  float uv[32];
  #pragma unroll
  for (int j = 0; j < 32; ++j) {
    int p = orient ? ((j << 5) | c) : ((c << 5) + j);
    uv[j] = ub[(size_t)p << 9];
  }
  float apr = expf((float)(c << 5) * lna);
  float sF = 0.f;
  #pragma unroll
  for (int j = 0; j < 32; ++j) {
    float ap = fmaxf(apr, 1e-20f);
    sF += uv[j] * bb / ap;
    apr *= a;
  }
  float aprB = expf((float)((31 - c) << 5) * lna);
  float sB = 0.f;
  #pragma unroll
  for (int j = 31; j >= 0; --j) {
    float ap = fmaxf(aprB, 1e-20f);
    sB += uv[j] * bb / ap;
    aprB *= a;
  }
  size_t idx = ((size_t)blockIdx.z * 32 + c) * 512 + d;
  carF[idx] = sF;
  carB[idx] = sB;
}

__global__ __launch_bounds__(256) void scanB_k(float* __restrict__ carF, float* __restrict__ carB)
{
  int id = blockIdx.x * 256 + threadIdx.x;
  int d = id & 511; int q = id >> 9;
  float* pF = carF + (size_t)q * 32 * 512 + d;
  float run = 0.f;
  #pragma unroll
  for (int c = 0; c < 32; ++c) { float v = pF[c * 512]; pF[c * 512] = run; run += v; }
  float* pB = carB + (size_t)q * 32 * 512 + d;
  run = 0.f;
  #pragma unroll
  for (int c = 31; c >= 0; --c) { float v = pB[c * 512]; pB[c * 512] = run; run += v; }
}

// row orientation: partial yp = 0.25*c*(s_fwd + s_bwd). grid (8,32,16), block 64
__global__ __launch_bounds__(64) void scanC_row_k(const float* __restrict__ u, const float* __restrict__ alog,
    const float* __restrict__ bvec, const float* __restrict__ cvec,
    const float* __restrict__ carF, const float* __restrict__ carB, float* __restrict__ yp)
{
  const int lane = threadIdx.x;
  const int cg = blockIdx.x, c = blockIdx.y, b = blockIdx.z;
  const int d = (cg << 6) + lane;
  const float a = sig_a(alog[d]);
  const float lna = logf(a);
  const float bb = bvec[d];
  const float sc = 0.25f * cvec[d];
  const float* ub = u + ((size_t)b << 19) + d;
  size_t cidx = ((size_t)(b * 2 + 0) * 32 + c) * 512 + d;

  float uv[32], sf[32];
  #pragma unroll
  for (int j = 0; j < 32; ++j) uv[j] = ub[(size_t)((c << 5) + j) << 9];

  float r = carF[cidx];
  float apr = expf((float)(c << 5) * lna);
  #pragma unroll
  for (int j = 0; j < 32; ++j) {
    float ap = fmaxf(apr, 1e-20f);
    r += uv[j] * bb / ap;
    sf[j] = r * ap;
    apr *= a;
  }
  float r2 = carB[cidx];
  float aprB = expf((float)((31 - c) << 5) * lna);
  float* yb = yp + ((size_t)b << 19) + d;
  #pragma unroll
  for (int j = 31; j >= 0; --j) {
    float ap = fmaxf(aprB, 1e-20f);
    r2 += uv[j] * bb / ap;
    yb[(size_t)((c << 5) + j) << 9] = sc * (sf[j] + r2 * ap);
    aprB *= a;
  }
}

// col orientation + combine: yo_bf16 = (yp + 0.25*c*(sf+sb) + d*u) * gate
__global__ __launch_bounds__(64) void scanC_col_k(const float* __restrict__ u, const float* __restrict__ alog,
    const float* __restrict__ bvec, const float* __restrict__ cvec, const float* __restrict__ dvec,
    const float* __restrict__ carF, const float* __restrict__ carB,
    const float* __restrict__ gate, const float* __restrict__ yp, __bf16* __restrict__ yo)
{
  const int lane = threadIdx.x;
  const int cg = blockIdx.x, c = blockIdx.y, b = blockIdx.z;
  const int d = (cg << 6) + lane;
  const float a = sig_a(alog[d]);
  const float lna = logf(a);
  const float bb = bvec[d];
  const float sc = 0.25f * cvec[d];
  const float dd = dvec[d];
  const float* ub = u + ((size_t)b << 19) + d;
  size_t cidx = ((size_t)(b * 2 + 1) * 32 + c) * 512 + d;

  float uv[32], sf[32];
  #pragma unroll
  for (int j = 0; j < 32; ++j) uv[j] = ub[(size_t)((j << 5) | c) << 9];

  float r = carF[cidx];
  float apr = expf((float)(c << 5) * lna);
  #pragma unroll
  for (int j = 0; j < 32; ++j) {
    float ap = fmaxf(apr, 1e-20f);
    r += uv[j] * bb / ap;
    sf[j] = r * ap;
    apr *= a;
  }
  float r2 = carB[cidx];
  float aprB = expf((float)((31 - c) << 5) * lna);
  const float* ypb = yp + ((size_t)b << 19) + d;
  const float* gb  = gate + ((size_t)b << 19) + d;
  __bf16* yob = yo + ((size_t)b << 19) + d;
  #pragma unroll
  for (int j = 31; j >= 0; --j) {
    float ap = fmaxf(aprB, 1e-20f);
    r2 += uv[j] * bb / ap;
    size_t off = (size_t)((j << 5) | c) << 9;
    float val = ypb[off] + sc * (sf[j] + r2 * ap) + dd * uv[j];
    yob[off] = (__bf16)(val * gb[off]);
    aprB *= a;
  }
}

// ---------------- mean over 1024 positions (bf16 in) -> (16, 512) fp32 ----------------
__global__ __launch_bounds__(64) void reduce_k(const __bf16* __restrict__ hn, float* __restrict__ out)
{
  int d = blockIdx.y * 64 + threadIdx.x;
  int b = blockIdx.x;
  const __bf16* p = hn + ((size_t)b << 19) + d;
  float s0 = 0.f, s1 = 0.f, s2 = 0.f, s3 = 0.f;
  for (int t = 0; t < 1024; t += 4) {
    s0 += (float)p[(size_t)(t+0) << 9];
    s1 += (float)p[(size_t)(t+1) << 9];
    s2 += (float)p[(size_t)(t+2) << 9];
    s3 += (float)p[(size_t)(t+3) << 9];
  }
  out[b * 512 + d] = (s0 + s1 + s2 + s3) * (1.f / 1024.f);
}

extern "C" void kernel_launch(void* const* d_in, const int* in_sizes, int n_in,
                              void* d_out, int out_size, void* d_ws, size_t ws_size,
                              hipStream_t stream)
{
  const float* tokens = (const float*)d_in[0];
  const float* in_w   = (const float*)d_in[1];
  const float* in_b   = (const float*)d_in[2];
  const float* nw     = (const float*)d_in[3];
  const float* nb     = (const float*)d_in[4];
  const float* iw     = (const float*)d_in[5];
  const float* ib     = (const float*)d_in[6];
  const float* cw     = (const float*)d_in[7];
  const float* cb     = (const float*)d_in[8];
  const float* al     = (const float*)d_in[9];
  const float* bbv    = (const float*)d_in[10];
  const float* ccv    = (const float*)d_in[11];
  const float* ddv    = (const float*)d_in[12];
  const float* ow     = (const float*)d_in[13];
  const float* obv    = (const float*)d_in[14];
  const float* onw    = (const float*)d_in[15];
  const float* onb    = (const float*)d_in[16];

  // workspace layout (161.5 MB total):
  float*  x    = (float*)d_ws;                       // fp32 residual (33.5 MB)
  __bf16* hy16 = (__bf16*)(x + PP);                  // bf16 h / yg / final-ln (16.8 MB)
  float*  xin  = (float*)(hy16 + PP);                // fp32 x_in; row-scan partial after conv (33.5)
  float*  gate = xin + PP;                           // fp32 gate (33.5); in_wT alias pre-loop
  float*  u    = gate + PP;                          // fp32 conv out (33.5); tokens-bf16 alias pre-loop
  __bf16* iwT  = (__bf16*)(u + PP);                  // 4x(1024x512) bf16 (4.2 MB)
  __bf16* owT  = iwT + (size_t)4 * 1024 * 512;       // 4x(512x512) bf16 (2.1 MB)
  float*  carF = (float*)(owT + (size_t)4 * 512 * 512);  // 16*2*32*512 fp32 (2 MB)
  float*  carB = carF + (size_t)16 * 2 * 32 * 512;       // (2 MB)
  __bf16* tb16 = (__bf16*)u;                         // tokens bf16 (25.2 MB, pre-loop only)
  __bf16* inwT = (__bf16*)gate;                      // in_proj_w^T bf16 (0.8 MB, pre-loop only)

  // --- weight/input conversion (once per launch, ~8 µs total) ---
  cvt_k<<<6144, 256, 0, stream>>>(tokens, tb16);                       // 16384*768 / 8 / 256
  tr_k<<<dim3(16, 24, 1), 256, 0, stream>>>(in_w, inwT, 768, 512, 0, 0);
  tr_k<<<dim3(32, 16, 4), 256, 0, stream>>>(iw, iwT, 512, 1024, (size_t)512*1024, (size_t)1024*512);
  tr_k<<<dim3(16, 16, 4), 256, 0, stream>>>(ow, owT, 512, 512, (size_t)512*512, (size_t)512*512);

  // x = tokens @ in_proj_w + b
  gemm_bf_k<<<dim3(4, 128), 256, 0, stream>>>(tb16, inwT, in_b, nullptr, x, nullptr, 512, 768, 0);

  for (int i = 0; i < 4; ++i) {
    ln_k<<<4096, 256, 0, stream>>>(x, nw + i*512, nb + i*512, hy16);
    gemm_bf_k<<<dim3(8, 128), 256, 0, stream>>>(hy16, iwT + (size_t)i*1024*512, ib + i*1024,
                                                nullptr, xin, gate, 1024, 512, 1);
    conv_k<<<8192, 256, 0, stream>>>(xin, cw + i*9*512, cb + i*512, u);
    scanA_k<<<dim3(8, 32, 32), 64, 0, stream>>>(u, al + i*512, bbv + i*512, carF, carB);
    scanB_k<<<64, 256, 0, stream>>>(carF, carB);
    scanC_row_k<<<dim3(8, 32, 16), 64, 0, stream>>>(u, al + i*512, bbv + i*512, ccv + i*512,
                                                    carF, carB, xin);
    scanC_col_k<<<dim3(8, 32, 16), 64, 0, stream>>>(u, al + i*512, bbv + i*512, ccv + i*512,
                                                    ddv + i*512, carF, carB, gate, xin, hy16);
    gemm_bf_k<<<dim3(4, 128), 256, 0, stream>>>(hy16, owT + (size_t)i*512*512, obv + i*512,
                                                x, x, nullptr, 512, 512, 2);
  }

  ln_k<<<4096, 256, 0, stream>>>(x, onw, onb, hy16);
  reduce_k<<<dim3(16, 8), 64, 0, stream>>>(hy16, (float*)d_out);
}

// Round 4
// 939.817 us; speedup vs baseline: 2.9827x; 1.0536x over previous
//
#include <hip/hip_runtime.h>
#include <hip/hip_bf16.h>
#include <math.h>

#define NPOS 16384   // B*H*W = 16*32*32
#define DD   512
#define PP   ((size_t)NPOS * DD)   // 8388608 elements per plane

typedef __bf16 bf16x8 __attribute__((ext_vector_type(8)));
typedef float  f32x4  __attribute__((ext_vector_type(4)));

// async global->LDS, 16 B per lane; LDS dest = wave-uniform base + lane*16
__device__ __forceinline__ void g2lds16(const void* g, void* l) {
  __builtin_amdgcn_global_load_lds(
      (__attribute__((address_space(1))) void*)g,
      (__attribute__((address_space(3))) void*)l, 16, 0, 0);
}

// ================= bf16 MFMA GEMM, double-buffered LDS =================
// C = A(MxK) @ Bt^T + bias.  A: MxK bf16 (ld K). Bt: NxK bf16 (ld K).
// epi 0: C0 fp32 (ld N) = acc + bias
// epi 1: N=1024; cols<512 -> C0 (ld 512); cols>=512 -> sigmoid -> C1 (ld 512)
// epi 2: C0 fp32 (ld N) = acc + bias + res
// Tiles: 128x128, BK=32. 4 waves, each 64x64 (4x4 MFMA 16x16x32 tiles).
// LDS 16B-slot XOR swizzle: LDS[r][s] = global[r][s ^ ((r>>1)&3)] (conflict-free, R3-verified).
// K-loop: buf cur computed on while buf cur^1 is being async-loaded (issued pre-compute,
// drained at the single per-iter barrier) -> exposed latency ~= load_lat - compute.
__global__ __launch_bounds__(256, 3) void gemm_bf_k(
    const __bf16* __restrict__ A, const __bf16* __restrict__ Bt,
    const float* __restrict__ bias, const float* __restrict__ res,
    float* __restrict__ C0, float* __restrict__ C1,
    int N, int K, int epi)
{
  __shared__ __bf16 Asm[2][128 * 32];
  __shared__ __bf16 Bsm[2][128 * 32];
  const int tid  = threadIdx.x;
  const int wave = tid >> 6;
  const int lane = tid & 63;
  const int quad = lane >> 4;
  const int l16  = lane & 15;
  const int bm = blockIdx.y * 128;
  const int bn = blockIdx.x * 128;
  const int wm = (wave >> 1) << 6;
  const int wn = (wave & 1) << 6;

  const int srow   = lane >> 2;                                  // row within 16-row stage
  const int schunk = (((lane & 3) ^ ((lane >> 3) & 3)) << 3);    // swizzled k-chunk (elements)

  f32x4 acc[4][4];
  const f32x4 z4 = {0.f, 0.f, 0.f, 0.f};
  #pragma unroll
  for (int i = 0; i < 4; ++i)
    #pragma unroll
    for (int j = 0; j < 4; ++j) acc[i][j] = z4;

  const __bf16* Ab = A  + (size_t)bm * K;
  const __bf16* Bb = Bt + (size_t)bn * K;
  const int nk = K >> 5;

  // stage K-block kb into LDS buffer buf (2 calls/wave per matrix, 16 rows each)
  #define STAGE(buf, kb)                                                              \
    {                                                                                 \
      const int k0s = (kb) << 5;                                                      \
      _Pragma("unroll")                                                               \
      for (int c = 0; c < 2; ++c) {                                                   \
        const int cc = wave * 2 + c;                                                  \
        g2lds16(Ab + (size_t)(cc * 16 + srow) * K + k0s + schunk, &Asm[buf][cc * 512]);\
        g2lds16(Bb + (size_t)(cc * 16 + srow) * K + k0s + schunk, &Bsm[buf][cc * 512]);\
      }                                                                               \
    }

  STAGE(0, 0)
  int cur = 0;
  for (int kb = 0; kb < nk; ++kb) {
    __syncthreads();                    // buf `cur` loads landed; buf cur^1 reads (iter kb-1) done
    if (kb + 1 < nk) STAGE(cur ^ 1, kb + 1)   // async prefetch next tile, in flight during compute
    bf16x8 af[4], bg[4];
    #pragma unroll
    for (int i = 0; i < 4; ++i) {
      int m = wm + i * 16 + l16;
      af[i] = *(const bf16x8*)(&Asm[cur][m * 32 + ((quad ^ ((m >> 1) & 3)) << 3)]);
    }
    #pragma unroll
    for (int j = 0; j < 4; ++j) {
      int n = wn + j * 16 + l16;
      bg[j] = *(const bf16x8*)(&Bsm[cur][n * 32 + ((quad ^ ((n >> 1) & 3)) << 3)]);
    }
    #pragma unroll
    for (int i = 0; i < 4; ++i)
      #pragma unroll
      for (int j = 0; j < 4; ++j)
        acc[i][j] = __builtin_amdgcn_mfma_f32_16x16x32_bf16(af[i], bg[j], acc[i][j], 0, 0, 0);
    cur ^= 1;
  }
  #undef STAGE

  // epilogue. C/D layout: col = lane&15, row = quad*4 + reg  [m89-verified]
  float* Co; int ldo, nb; bool dosig = false;
  if (epi == 1) {
    ldo = 512;
    if (bn >= 512) { Co = C1; nb = bn - 512; dosig = true; }
    else           { Co = C0; nb = bn; }
  } else { Co = C0; ldo = N; nb = bn; }

  #pragma unroll
  for (int j = 0; j < 4; ++j) {
    const int col = wn + j * 16 + l16;
    const float bv = bias[bn + col];
    #pragma unroll
    for (int i = 0; i < 4; ++i) {
      const int row0 = bm + wm + i * 16 + quad * 4;
      #pragma unroll
      for (int r = 0; r < 4; ++r) {
        float v = acc[i][j][r] + bv;
        if (dosig) v = 1.f / (1.f + expf(-v));
        size_t off = (size_t)(row0 + r) * ldo + nb + col;
        if (epi == 2) v += res[off];
        Co[off] = v;
      }
    }
  }
}

// ---------------- fp32 -> bf16 elementwise (tokens) ----------------
__global__ __launch_bounds__(256) void cvt_k(const float* __restrict__ s, __bf16* __restrict__ d)
{
  size_t i = ((size_t)blockIdx.x * 256 + threadIdx.x) * 8;
  float4 a = *(const float4*)(s + i);
  float4 b = *(const float4*)(s + i + 4);
  bf16x8 v;
  v[0] = (__bf16)a.x; v[1] = (__bf16)a.y; v[2] = (__bf16)a.z; v[3] = (__bf16)a.w;
  v[4] = (__bf16)b.x; v[5] = (__bf16)b.y; v[6] = (__bf16)b.z; v[7] = (__bf16)b.w;
  *(bf16x8*)(d + i) = v;
}

// ---------------- transpose KxN fp32 -> NxK bf16 (weights) ----------------
__global__ __launch_bounds__(256) void tr_k(const float* __restrict__ src, __bf16* __restrict__ dst,
                                            int K, int N, size_t sstr, size_t dstr)
{
  __shared__ float t[32][33];
  const float* s = src + blockIdx.z * sstr;
  __bf16* d = dst + blockIdx.z * dstr;
  int n0 = blockIdx.x * 32, k0 = blockIdx.y * 32;
  int tx = threadIdx.x & 31, ty = threadIdx.x >> 5;   // 32x8
  #pragma unroll
  for (int i = 0; i < 4; ++i)
    t[ty + i * 8][tx] = s[(size_t)(k0 + ty + i * 8) * N + n0 + tx];
  __syncthreads();
  #pragma unroll
  for (int i = 0; i < 4; ++i)
    d[(size_t)(n0 + ty + i * 8) * K + k0 + tx] = (__bf16)t[tx][ty + i * 8];
}

// ---------------- LayerNorm over D=512, one wave per position, bf16 out ----------------
__global__ __launch_bounds__(256) void ln_k(const float* __restrict__ x, const float* __restrict__ w,
                                            const float* __restrict__ bv, __bf16* __restrict__ out)
{
  int gw = (blockIdx.x * 256 + threadIdx.x) >> 6;   // position
  int lane = threadIdx.x & 63;
  const float* xp = x + ((size_t)gw << 9) + lane * 8;
  float4 u0 = *(const float4*)xp;
  float4 u1 = *(const float4*)(xp + 4);
  float v[8] = {u0.x,u0.y,u0.z,u0.w,u1.x,u1.y,u1.z,u1.w};
  float s = 0.f;
  #pragma unroll
  for (int j = 0; j < 8; ++j) s += v[j];
  #pragma unroll
  for (int off = 32; off; off >>= 1) s += __shfl_xor(s, off, 64);
  float mu = s * (1.f/512.f);
  float q = 0.f;
  #pragma unroll
  for (int j = 0; j < 8; ++j) { float d = v[j] - mu; q += d*d; }
  #pragma unroll
  for (int off = 32; off; off >>= 1) q += __shfl_xor(q, off, 64);
  float rstd = rsqrtf(q * (1.f/512.f) + 1e-5f);
  int dch = lane * 8;
  float4 w0 = *(const float4*)(w + dch),  w1 = *(const float4*)(w + dch + 4);
  float4 b0 = *(const float4*)(bv + dch), b1 = *(const float4*)(bv + dch + 4);
  float wv[8] = {w0.x,w0.y,w0.z,w0.w,w1.x,w1.y,w1.z,w1.w};
  float bb[8] = {b0.x,b0.y,b0.z,b0.w,b1.x,b1.y,b1.z,b1.w};
  bf16x8 ov;
  #pragma unroll
  for (int j = 0; j < 8; ++j) ov[j] = (__bf16)((v[j] - mu) * rstd * wv[j] + bb[j]);
  *(bf16x8*)(out + ((size_t)gw << 9) + dch) = ov;
}

// ---------------- depthwise 3x3 conv + bias + SiLU; xin plane (ld 512) -> u ----------------
__global__ __launch_bounds__(256) void conv_k(const float* __restrict__ xin, const float* __restrict__ cw,
                                              const float* __restrict__ cb, float* __restrict__ u)
{
  int id = blockIdx.x * 256 + threadIdx.x;
  int dq = id & 127;
  int pos = id >> 7;
  int ww = pos & 31, hh = (pos >> 5) & 31, b = pos >> 10;
  int d = dq << 2;
  float4 acc = *(const float4*)(cb + d);
  #pragma unroll
  for (int kh = 0; kh < 3; ++kh) {
    int yy = hh + kh - 1;
    if (yy < 0 || yy > 31) continue;
    #pragma unroll
    for (int kw = 0; kw < 3; ++kw) {
      int xx = ww + kw - 1;
      if (xx < 0 || xx > 31) continue;
      float4 xv = *(const float4*)(xin + ((size_t)((b << 10) + (yy << 5) + xx) << 9) + d);
      float4 wv = *(const float4*)(cw + (size_t)((kh*3 + kw) << 9) + d);
      acc.x = fmaf(xv.x, wv.x, acc.x);
      acc.y = fmaf(xv.y, wv.y, acc.y);
      acc.z = fmaf(xv.z, wv.z, acc.z);
      acc.w = fmaf(xv.w, wv.w, acc.w);
    }
  }
  acc.x = acc.x / (1.f + expf(-acc.x));
  acc.y = acc.y / (1.f + expf(-acc.y));
  acc.z = acc.z / (1.f + expf(-acc.z));
  acc.w = acc.w / (1.f + expf(-acc.w));
  *(float4*)(u + ((size_t)pos << 9) + d) = acc;
}

// ================= Parallel clamped-cumsum scan (exact reference semantics) =================
__device__ __forceinline__ float sig_a(float al) {
  float a = 1.f / (1.f + expf(-al));
  return fminf(fmaxf(a, 1e-4f), 1.f - 1e-4f);
}

// grid (8 cg, 32 chunk, 32 = b*2+orient), block 64
__global__ __launch_bounds__(64) void scanA_k(const float* __restrict__ u, const float* __restrict__ alog,
    const float* __restrict__ bvec, float* __restrict__ carF, float* __restrict__ carB)
{
  const int lane = threadIdx.x;
  const int cg = blockIdx.x, c = blockIdx.y;
  const int b = blockIdx.z >> 1, orient = blockIdx.z & 1;
  const int d = (cg << 6) + lane;
  const float a = sig_a(alog[d]);
  const float lna = logf(a);
  const float bb = bvec[d];
  const float* ub = u + ((size_t)b << 19) + d;

  float uv[32];
  #pragma unroll
  for (int j = 0; j < 32; ++j) {
    int p = orient ? ((j << 5) | c) : ((c << 5) + j);
    uv[j] = ub[(size_t)p << 9];
  }
  float apr = expf((float)(c << 5) * lna);
  float sF = 0.f;
  #pragma unroll
  for (int j = 0; j < 32; ++j) {
    float ap = fmaxf(apr, 1e-20f);
    sF += uv[j] * bb / ap;
    apr *= a;
  }
  float aprB = expf((float)((31 - c) << 5) * lna);
  float sB = 0.f;
  #pragma unroll
  for (int j = 31; j >= 0; --j) {
    float ap = fmaxf(aprB, 1e-20f);
    sB += uv[j] * bb / ap;
    aprB *= a;
  }
  size_t idx = ((size_t)blockIdx.z * 32 + c) * 512 + d;
  carF[idx] = sF;
  carB[idx] = sB;
}

__global__ __launch_bounds__(256) void scanB_k(float* __restrict__ carF, float* __restrict__ carB)
{
  int id = blockIdx.x * 256 + threadIdx.x;
  int d = id & 511; int q = id >> 9;
  float* pF = carF + (size_t)q * 32 * 512 + d;
  float run = 0.f;
  #pragma unroll
  for (int c = 0; c < 32; ++c) { float v = pF[c * 512]; pF[c * 512] = run; run += v; }
  float* pB = carB + (size_t)q * 32 * 512 + d;
  run = 0.f;
  #pragma unroll
  for (int c = 31; c >= 0; --c) { float v = pB[c * 512]; pB[c * 512] = run; run += v; }
}

// row orientation: partial yp = 0.25*c*(s_fwd + s_bwd). grid (8,32,16), block 64
__global__ __launch_bounds__(64) void scanC_row_k(const float* __restrict__ u, const float* __restrict__ alog,
    const float* __restrict__ bvec, const float* __restrict__ cvec,
    const float* __restrict__ carF, const float* __restrict__ carB, float* __restrict__ yp)
{
  const int lane = threadIdx.x;
  const int cg = blockIdx.x, c = blockIdx.y, b = blockIdx.z;
  const int d = (cg << 6) + lane;
  const float a = sig_a(alog[d]);
  const float lna = logf(a);
  const float bb = bvec[d];
  const float sc = 0.25f * cvec[d];
  const float* ub = u + ((size_t)b << 19) + d;
  size_t cidx = ((size_t)(b * 2 + 0) * 32 + c) * 512 + d;

  float uv[32], sf[32];
  #pragma unroll
  for (int j = 0; j < 32; ++j) uv[j] = ub[(size_t)((c << 5) + j) << 9];

  float r = carF[cidx];
  float apr = expf((float)(c << 5) * lna);
  #pragma unroll
  for (int j = 0; j < 32; ++j) {
    float ap = fmaxf(apr, 1e-20f);
    r += uv[j] * bb / ap;
    sf[j] = r * ap;
    apr *= a;
  }
  float r2 = carB[cidx];
  float aprB = expf((float)((31 - c) << 5) * lna);
  float* yb = yp + ((size_t)b << 19) + d;
  #pragma unroll
  for (int j = 31; j >= 0; --j) {
    float ap = fmaxf(aprB, 1e-20f);
    r2 += uv[j] * bb / ap;
    yb[(size_t)((c << 5) + j) << 9] = sc * (sf[j] + r2 * ap);
    aprB *= a;
  }
}

// col orientation + combine: yo_bf16 = (yp + 0.25*c*(sf+sb) + d*u) * gate
__global__ __launch_bounds__(64) void scanC_col_k(const float* __restrict__ u, const float* __restrict__ alog,
    const float* __restrict__ bvec, const float* __restrict__ cvec, const float* __restrict__ dvec,
    const float* __restrict__ carF, const float* __restrict__ carB,
    const float* __restrict__ gate, const float* __restrict__ yp, __bf16* __restrict__ yo)
{
  const int lane = threadIdx.x;
  const int cg = blockIdx.x, c = blockIdx.y, b = blockIdx.z;
  const int d = (cg << 6) + lane;
  const float a = sig_a(alog[d]);
  const float lna = logf(a);
  const float bb = bvec[d];
  const float sc = 0.25f * cvec[d];
  const float dd = dvec[d];
  const float* ub = u + ((size_t)b << 19) + d;
  size_t cidx = ((size_t)(b * 2 + 1) * 32 + c) * 512 + d;

  float uv[32], sf[32];
  #pragma unroll
  for (int j = 0; j < 32; ++j) uv[j] = ub[(size_t)((j << 5) | c) << 9];

  float r = carF[cidx];
  float apr = expf((float)(c << 5) * lna);
  #pragma unroll
  for (int j = 0; j < 32; ++j) {
    float ap = fmaxf(apr, 1e-20f);
    r += uv[j] * bb / ap;
    sf[j] = r * ap;
    apr *= a;
  }
  float r2 = carB[cidx];
  float aprB = expf((float)((31 - c) << 5) * lna);
  const float* ypb = yp + ((size_t)b << 19) + d;
  const float* gb  = gate + ((size_t)b << 19) + d;
  __bf16* yob = yo + ((size_t)b << 19) + d;
  #pragma unroll
  for (int j = 31; j >= 0; --j) {
    float ap = fmaxf(aprB, 1e-20f);
    r2 += uv[j] * bb / ap;
    size_t off = (size_t)((j << 5) | c) << 9;
    float val = ypb[off] + sc * (sf[j] + r2 * ap) + dd * uv[j];
    yob[off] = (__bf16)(val * gb[off]);
    aprB *= a;
  }
}

// ---------------- mean over 1024 positions (bf16 in) -> (16, 512) fp32 ----------------
__global__ __launch_bounds__(64) void reduce_k(const __bf16* __restrict__ hn, float* __restrict__ out)
{
  int d = blockIdx.y * 64 + threadIdx.x;
  int b = blockIdx.x;
  const __bf16* p = hn + ((size_t)b << 19) + d;
  float s0 = 0.f, s1 = 0.f, s2 = 0.f, s3 = 0.f;
  for (int t = 0; t < 1024; t += 4) {
    s0 += (float)p[(size_t)(t+0) << 9];
    s1 += (float)p[(size_t)(t+1) << 9];
    s2 += (float)p[(size_t)(t+2) << 9];
    s3 += (float)p[(size_t)(t+3) << 9];
  }
  out[b * 512 + d] = (s0 + s1 + s2 + s3) * (1.f / 1024.f);
}

extern "C" void kernel_launch(void* const* d_in, const int* in_sizes, int n_in,
                              void* d_out, int out_size, void* d_ws, size_t ws_size,
                              hipStream_t stream)
{
  const float* tokens = (const float*)d_in[0];
  const float* in_w   = (const float*)d_in[1];
  const float* in_b   = (const float*)d_in[2];
  const float* nw     = (const float*)d_in[3];
  const float* nb     = (const float*)d_in[4];
  const float* iw     = (const float*)d_in[5];
  const float* ib     = (const float*)d_in[6];
  const float* cw     = (const float*)d_in[7];
  const float* cb     = (const float*)d_in[8];
  const float* al     = (const float*)d_in[9];
  const float* bbv    = (const float*)d_in[10];
  const float* ccv    = (const float*)d_in[11];
  const float* ddv    = (const float*)d_in[12];
  const float* ow     = (const float*)d_in[13];
  const float* obv    = (const float*)d_in[14];
  const float* onw    = (const float*)d_in[15];
  const float* onb    = (const float*)d_in[16];

  // workspace layout (161.5 MB total):
  float*  x    = (float*)d_ws;                       // fp32 residual (33.5 MB)
  __bf16* hy16 = (__bf16*)(x + PP);                  // bf16 h / yg / final-ln (16.8 MB)
  float*  xin  = (float*)(hy16 + PP);                // fp32 x_in; row-scan partial after conv (33.5)
  float*  gate = xin + PP;                           // fp32 gate (33.5); in_wT alias pre-loop
  float*  u    = gate + PP;                          // fp32 conv out (33.5); tokens-bf16 alias pre-loop
  __bf16* iwT  = (__bf16*)(u + PP);                  // 4x(1024x512) bf16 (4.2 MB)
  __bf16* owT  = iwT + (size_t)4 * 1024 * 512;       // 4x(512x512) bf16 (2.1 MB)
  float*  carF = (float*)(owT + (size_t)4 * 512 * 512);  // 16*2*32*512 fp32 (2 MB)
  float*  carB = carF + (size_t)16 * 2 * 32 * 512;       // (2 MB)
  __bf16* tb16 = (__bf16*)u;                         // tokens bf16 (25.2 MB, pre-loop only)
  __bf16* inwT = (__bf16*)gate;                      // in_proj_w^T bf16 (0.8 MB, pre-loop only)

  // --- weight/input conversion (once per launch) ---
  cvt_k<<<6144, 256, 0, stream>>>(tokens, tb16);
  tr_k<<<dim3(16, 24, 1), 256, 0, stream>>>(in_w, inwT, 768, 512, 0, 0);
  tr_k<<<dim3(32, 16, 4), 256, 0, stream>>>(iw, iwT, 512, 1024, (size_t)512*1024, (size_t)1024*512);
  tr_k<<<dim3(16, 16, 4), 256, 0, stream>>>(ow, owT, 512, 512, (size_t)512*512, (size_t)512*512);

  // x = tokens @ in_proj_w + b
  gemm_bf_k<<<dim3(4, 128), 256, 0, stream>>>(tb16, inwT, in_b, nullptr, x, nullptr, 512, 768, 0);

  for (int i = 0; i < 4; ++i) {
    ln_k<<<4096, 256, 0, stream>>>(x, nw + i*512, nb + i*512, hy16);
    gemm_bf_k<<<dim3(8, 128), 256, 0, stream>>>(hy16, iwT + (size_t)i*1024*512, ib + i*1024,
                                                nullptr, xin, gate, 1024, 512, 1);
    conv_k<<<8192, 256, 0, stream>>>(xin, cw + i*9*512, cb + i*512, u);
    scanA_k<<<dim3(8, 32, 32), 64, 0, stream>>>(u, al + i*512, bbv + i*512, carF, carB);
    scanB_k<<<64, 256, 0, stream>>>(carF, carB);
    scanC_row_k<<<dim3(8, 32, 16), 64, 0, stream>>>(u, al + i*512, bbv + i*512, ccv + i*512,
                                                    carF, carB, xin);
    scanC_col_k<<<dim3(8, 32, 16), 64, 0, stream>>>(u, al + i*512, bbv + i*512, ccv + i*512,
                                                    ddv + i*512, carF, carB, gate, xin, hy16);
    gemm_bf_k<<<dim3(4, 128), 256, 0, stream>>>(hy16, owT + (size_t)i*512*512, obv + i*512,
                                                x, x, nullptr, 512, 512, 2);
  }

  ln_k<<<4096, 256, 0, stream>>>(x, onw, onb, hy16);
  reduce_k<<<dim3(16, 8), 64, 0, stream>>>(hy16, (float*)d_out);
}